// Round 1
// baseline (126.168 us; speedup 1.0000x reference)
//
#include <hip/hip_runtime.h>

namespace {
constexpr int B = 8, H = 128, W = 128, C = 128;
constexpr int DMAX = 4, MO = 9, NOFF = 81;
constexpr int ROWS = 4;               // output rows per block
constexpr int CK = 4;                 // channels per LDS chunk
constexpr int NCHUNK = C / CK;        // 32
constexpr int F2R = ROWS + 2 * DMAX;  // 12 F2 rows staged
constexpr int F2P = 140;              // 136 + 4 pad (bank spread)
constexpr int F1P = 132;              // 128 + 4 pad
constexpr int NT = 576;               // 9 waves, 4r x 9dy x 16wg = 576 exactly
}

__global__ __launch_bounds__(NT) void costvol_kernel(
    const float* __restrict__ F1, const float* __restrict__ F2,
    float* __restrict__ out)
{
  __shared__ __align__(16) float sF1[CK][ROWS][F1P];  // 8.4 KB
  __shared__ __align__(16) float sF2[CK][F2R][F2P];   // 26.9 KB

  // b = lin&7: one batch per XCD (round-robin dispatch), consecutive
  // row-tiles of the same batch share halo rows on the same XCD's L2.
  const int lin = blockIdx.x;
  const int b  = lin & 7;
  const int rt = lin >> 3;
  const int h0 = rt * ROWS;

  const int tid = threadIdx.x;
  const int r   = tid / 144;          // output row within tile (0..3)
  const int t2  = tid - r * 144;
  const int dyi = t2 >> 4;            // displacement row 0..8
  const int wg  = t2 & 15;            // pixel group (8 px)
  const int w0  = wg * 8;
  const int ry  = r + dyi;            // row in sF2 (fy = h0-4+ry = h+dyi-4)

  float acc[72];
#pragma unroll
  for (int i = 0; i < 72; ++i) acc[i] = 0.f;

  const size_t f1base = ((size_t)b * H + h0) * W * C;

  for (int ch = 0; ch < NCHUNK; ++ch) {
    const int c0 = ch * CK;

    // ---- stage F1 rows h0..h0+3, channels c0..c0+3: 512 float4 slots
    for (int i = tid; i < ROWS * W; i += NT) {
      const int rr = i >> 7;
      const int w  = i & 127;
      const float4 v = *reinterpret_cast<const float4*>(
          F1 + f1base + ((size_t)rr * W + w) * C + c0);
      sF1[0][rr][w] = v.x; sF1[1][rr][w] = v.y;
      sF1[2][rr][w] = v.z; sF1[3][rr][w] = v.w;
    }
    // ---- stage F2 rows h0-4..h0+7 (zero-padded), 136 cols: 1632 slots
    for (int i = tid; i < F2R * 136; i += NT) {
      const int ryi = i / 136;
      const int cx  = i - ryi * 136;
      const int fy  = h0 - DMAX + ryi;
      const int fx  = cx - DMAX;
      float4 v = make_float4(0.f, 0.f, 0.f, 0.f);
      if ((unsigned)fy < (unsigned)H && (unsigned)fx < (unsigned)W) {
        v = *reinterpret_cast<const float4*>(
            F2 + (((size_t)b * H + fy) * W + fx) * C + c0);
      }
      sF2[0][ryi][cx] = v.x; sF2[1][ryi][cx] = v.y;
      sF2[2][ryi][cx] = v.z; sF2[3][ryi][cx] = v.w;
    }
    __syncthreads();

    // ---- compute: per channel, 8 px x 9 dx register tile (72 FMA per
    // 6 ds_read_b128 -> 1:12 LDS:FMA ratio)
#pragma unroll
    for (int cc = 0; cc < CK; ++cc) {
      float f1v[8], f2v[16];
      *reinterpret_cast<float4*>(&f1v[0]) =
          *reinterpret_cast<const float4*>(&sF1[cc][r][w0]);
      *reinterpret_cast<float4*>(&f1v[4]) =
          *reinterpret_cast<const float4*>(&sF1[cc][r][w0 + 4]);
      *reinterpret_cast<float4*>(&f2v[0]) =
          *reinterpret_cast<const float4*>(&sF2[cc][ry][w0]);
      *reinterpret_cast<float4*>(&f2v[4]) =
          *reinterpret_cast<const float4*>(&sF2[cc][ry][w0 + 4]);
      *reinterpret_cast<float4*>(&f2v[8]) =
          *reinterpret_cast<const float4*>(&sF2[cc][ry][w0 + 8]);
      *reinterpret_cast<float4*>(&f2v[12]) =
          *reinterpret_cast<const float4*>(&sF2[cc][ry][w0 + 12]);
#pragma unroll
      for (int p = 0; p < 8; ++p) {
#pragma unroll
        for (int dxi = 0; dxi < MO; ++dxi) {
          acc[p * MO + dxi] = fmaf(f1v[p], f2v[p + dxi], acc[p * MO + dxi]);
        }
      }
    }
    __syncthreads();
  }

  // ---- epilogue: mean (x 1/128), leaky_relu(0.1), store
  const int h = h0 + r;
  float* obase = out + (((size_t)b * H + h) * W + w0) * NOFF + dyi * MO;
#pragma unroll
  for (int p = 0; p < 8; ++p) {
#pragma unroll
    for (int dxi = 0; dxi < MO; ++dxi) {
      float m = acc[p * MO + dxi] * 0.0078125f;  // /128 exact
      m = (m > 0.f) ? m : 0.1f * m;              // leaky_relu
      obase[(size_t)p * NOFF + dxi] = m;
    }
  }
}

extern "C" void kernel_launch(void* const* d_in, const int* in_sizes, int n_in,
                              void* d_out, int out_size, void* d_ws, size_t ws_size,
                              hipStream_t stream) {
  const float* F1 = (const float*)d_in[0];
  const float* F2 = (const float*)d_in[1];
  float* out = (float*)d_out;
  dim3 grid(B * (H / ROWS));  // 256 blocks = 1 per CU
  dim3 block(NT);             // 576 threads = 9 waves
  hipLaunchKernelGGL(costvol_kernel, grid, block, 0, stream, F1, F2, out);
}

// Round 2
// 73.870 us; speedup vs baseline: 1.7080x; 1.7080x over previous
//
#include <hip/hip_runtime.h>

typedef __attribute__((ext_vector_type(8))) short bf16x8;
typedef __attribute__((ext_vector_type(4))) float f32x4;

namespace {
constexpr int B = 8, H = 128, W = 128, C = 128;
constexpr int MO = 9, NOFF = 81;
constexpr int ROWS = 4;     // output rows per block
constexpr int WCOLS = 32;   // output cols per block
constexpr int F2R = 12;     // ROWS + 8 staged F2 rows
constexpr int F2S = 48;     // staged F2 col pitch (40 real + 8 pad)
constexpr int CK = 32;      // channels per chunk (one MFMA k-step)
constexpr int NCH = C / CK; // 4
constexpr int NT = 512;     // 8 waves
}

__device__ inline unsigned bfpack2(float a, float b) {
  // round-to-nearest-even fp32->bf16, packed low|high
  unsigned ua = __builtin_bit_cast(unsigned, a);
  unsigned ub = __builtin_bit_cast(unsigned, b);
  ua += 0x7fffu + ((ua >> 16) & 1u);
  ub += 0x7fffu + ((ub >> 16) & 1u);
  return (ua >> 16) | (ub & 0xffff0000u);
}

__global__ __launch_bounds__(NT) void costvol_mfma_kernel(
    const float* __restrict__ F1, const float* __restrict__ F2,
    float* __restrict__ out)
{
  __shared__ __align__(16) short sF2[F2R * F2S * CK];   // 36864 B
  __shared__ __align__(16) short sF1[ROWS * WCOLS * CK]; //  8192 B

  // b = lin&7 -> one batch per XCD; rt-fastest -> 2.6MB F2 col-strip stays in L2
  const int lin  = blockIdx.x;
  const int b    = lin & 7;
  const int tile = lin >> 3;          // 0..127
  const int rt   = tile & 31;         // row tile (4 rows)
  const int wt   = tile >> 5;         // col tile (32 cols), 0..3
  const int h0   = rt * ROWS;
  const int wb0  = wt * WCOLS;

  const int tid  = threadIdx.x;
  const int wv   = tid >> 6;
  const int lane = tid & 63;
  const int j    = lane & 15;         // MFMA m/n index within fragment
  const int kq   = lane >> 4;         // k-quarter
  const int r    = wv >> 1;           // output row within tile (0..3)
  const int w0L  = (wv & 1) * 16;     // px-tile base within block (0 or 16)

  f32x4 acc[9][2];
#pragma unroll
  for (int d = 0; d < 9; ++d) { acc[d][0] = {0,0,0,0}; acc[d][1] = {0,0,0,0}; }

  const size_t f1row = ((size_t)b * H + h0) * W;   // + r*W + px, *C
  const size_t f2bat = (size_t)b * H;

  for (int ch = 0; ch < NCH; ++ch) {
    const int c0 = ch * CK;
    if (ch) __syncthreads();   // previous compute done before overwrite

    // ---- stage F2 rows h0-4..h0+7, cols wb0-4..wb0+35 (s=0..39; 40..47 pad=0)
    // idx -> (ry, s, kg4): 12*48*8 = 4608 = 9 * 512
#pragma unroll
    for (int it = 0; it < 9; ++it) {
      const int idx = tid + it * NT;
      const int kg  = idx & 7;
      const int ry  = idx / (F2S * 8);
      const int s   = (idx - ry * (F2S * 8)) >> 3;
      const int fy  = h0 - 4 + ry;
      const int fx  = wb0 - 4 + s;
      float4 v = make_float4(0.f, 0.f, 0.f, 0.f);
      if (s < 40 && (unsigned)fy < (unsigned)H && (unsigned)fx < (unsigned)W) {
        v = *reinterpret_cast<const float4*>(
            F2 + ((f2bat + fy) * W + fx) * C + c0 + kg * 4);
      }
      uint2 p;
      p.x = bfpack2(v.x, v.y);
      p.y = bfpack2(v.z, v.w);
      *reinterpret_cast<uint2*>(&sF2[(ry * F2S + s) * CK + kg * 4]) = p;
    }
    // ---- stage F1 rows h0..h0+3, cols wb0..wb0+31: 4*32*8 = 1024 = 2 * 512
#pragma unroll
    for (int it = 0; it < 2; ++it) {
      const int idx = tid + it * NT;
      const int kg  = idx & 7;
      const int px  = (idx >> 3) & 31;
      const int rr  = idx >> 8;
      const float4 v = *reinterpret_cast<const float4*>(
          F1 + (f1row + rr * W + wb0 + px) * C + c0 + kg * 4);
      uint2 p;
      p.x = bfpack2(v.x, v.y);
      p.y = bfpack2(v.z, v.w);
      *reinterpret_cast<uint2*>(&sF1[(rr * WCOLS + px) * CK + kg * 4]) = p;
    }
    __syncthreads();

    // ---- MFMA: A = F1[16 px x 32k], B tiles = F2 cols [w0L..+15], [w0L+16..+31]
    const bf16x8 a = *reinterpret_cast<const bf16x8*>(
        &sF1[(r * WCOLS + w0L + j) * CK + kq * 8]);
#pragma unroll
    for (int dy = 0; dy < 9; ++dy) {
      const short* brow = &sF2[((r + dy) * F2S + w0L + j) * CK + kq * 8];
      const bf16x8 b0 = *reinterpret_cast<const bf16x8*>(brow);
      const bf16x8 b1 = *reinterpret_cast<const bf16x8*>(brow + 16 * CK);
      acc[dy][0] = __builtin_amdgcn_mfma_f32_16x16x32_bf16(a, b0, acc[dy][0], 0, 0, 0);
      acc[dy][1] = __builtin_amdgcn_mfma_f32_16x16x32_bf16(a, b1, acc[dy][1], 0, 0, 0);
    }
  }

  // ---- epilogue: band extract, mean, leaky_relu, store
  // D layout (m89): n = lane&15 = j (F2 col), m = (lane>>4)*4 + reg = px i
  const int h = h0 + r;
  float* outb = out + (((size_t)b * H + h) * W + wb0 + w0L) * NOFF;
#pragma unroll
  for (int dy = 0; dy < 9; ++dy) {
#pragma unroll
    for (int t = 0; t < 2; ++t) {
#pragma unroll
      for (int reg = 0; reg < 4; ++reg) {
        const int i   = kq * 4 + reg;
        const int dxi = j + t * 16 - i;
        if (dxi >= 0 && dxi <= 8) {
          float m = acc[dy][t][reg] * 0.0078125f;   // /128
          m = (m > 0.f) ? m : 0.1f * m;             // leaky_relu(0.1)
          outb[(size_t)i * NOFF + dy * MO + dxi] = m;
        }
      }
    }
  }
}

extern "C" void kernel_launch(void* const* d_in, const int* in_sizes, int n_in,
                              void* d_out, int out_size, void* d_ws, size_t ws_size,
                              hipStream_t stream) {
  const float* F1 = (const float*)d_in[0];
  const float* F2 = (const float*)d_in[1];
  float* out = (float*)d_out;
  dim3 grid(B * (H / ROWS) * (W / WCOLS));  // 8 * 32 * 4 = 1024 blocks
  dim3 block(NT);                           // 512 threads = 8 waves
  hipLaunchKernelGGL(costvol_mfma_kernel, grid, block, 0, stream, F1, F2, out);
}

// Round 3
// 50.395 us; speedup vs baseline: 2.5036x; 1.4658x over previous
//
#include <hip/hip_runtime.h>

typedef __attribute__((ext_vector_type(8))) short bf16x8;
typedef __attribute__((ext_vector_type(4))) float f32x4;
typedef __attribute__((ext_vector_type(4))) unsigned u32x4;

namespace {
constexpr int B = 8, H = 128, W = 128, C = 128;
constexpr int MO = 9, NOFF = 81;
constexpr int ROWS = 4;          // output rows per block (1 per wave)
constexpr int WCOLS = 16;        // output cols per block
constexpr int F2R = 12;          // staged F2 rows (4 + 2*4 halo)
constexpr int F2S = 32;          // F2 col pitch: 24 real + 8 don't-care
constexpr int SREAL = 24;        // real staged cols (fx = wb0-4 .. wb0+19)
constexpr int CK = 32;           // channels per chunk (one MFMA K)
constexpr int NCH = C / CK;      // 4
constexpr int NT = 256;          // 4 waves
constexpr int NLD = 9;           // 12*24*8 / 256 staging float4 per thread
constexpr int RSTR = F2S * CK;   // shorts per staged F2 row (1024)
}

__device__ inline unsigned bfpack2(float a, float b) {
  // RTNE fp32->bf16 pair, packed (a=lo, b=hi)
  unsigned ua = __builtin_bit_cast(unsigned, a);
  unsigned ub = __builtin_bit_cast(unsigned, b);
  ua += 0x7fffu + ((ua >> 16) & 1u);
  ub += 0x7fffu + ((ub >> 16) & 1u);
  return (ua >> 16) | (ub & 0xffff0000u);
}

__global__ __launch_bounds__(NT, 3) void costvol_kernel(
    const float* __restrict__ F1, const float* __restrict__ F2,
    float* __restrict__ out)
{
  __shared__ __align__(16) short sF2[2][F2R * RSTR];  // 2 x 24 KB

  // b = lin&7: one batch per XCD; rt fastest: consecutive blocks share halo rows
  const int lin  = blockIdx.x;
  const int b    = lin & 7;
  const int tile = lin >> 3;      // 0..255
  const int rt   = tile & 31;
  const int wt   = tile >> 5;     // 0..7
  const int h0   = rt * ROWS;
  const int wb0  = wt * WCOLS;

  const int tid  = threadIdx.x;
  const int r    = tid >> 6;      // wave index = output row in tile
  const int lane = tid & 63;
  const int j    = lane & 15;     // MFMA m/n index
  const int kq   = lane >> 4;     // k-quarter

  // ---- loop-invariant staging decode: (ry, s, kg) per slot
  int gofs[NLD]; int lofs[NLD]; bool inb[NLD];
#pragma unroll
  for (int it = 0; it < NLD; ++it) {
    const int idx  = tid + it * NT;     // 0..2303
    const int kg   = idx & 7;
    const int slot = idx >> 3;          // 0..287
    const int ry   = slot / SREAL;
    const int s    = slot - ry * SREAL;
    const int fy   = h0 - 4 + ry;
    const int fx   = wb0 - 4 + s;
    inb[it]  = ((unsigned)fy < (unsigned)H) && ((unsigned)fx < (unsigned)W);
    gofs[it] = ((b * H + fy) * W + fx) * C + kg * 4;
    lofs[it] = (ry * F2S + s) * CK + kg * 4;
  }

  auto stage_load = [&](int ch, float4* ld) {
#pragma unroll
    for (int it = 0; it < NLD; ++it) {
      float4 v = make_float4(0.f, 0.f, 0.f, 0.f);
      if (inb[it]) v = *reinterpret_cast<const float4*>(F2 + gofs[it] + ch * CK);
      ld[it] = v;
    }
  };
  auto stage_store = [&](int buf, const float4* ld) {
#pragma unroll
    for (int it = 0; it < NLD; ++it) {
      uint2 p;
      p.x = bfpack2(ld[it].x, ld[it].y);
      p.y = bfpack2(ld[it].z, ld[it].w);
      *reinterpret_cast<uint2*>(&sF2[buf][lofs[it]]) = p;
    }
  };

  f32x4 acc[9][2];
#pragma unroll
  for (int d = 0; d < 9; ++d) { acc[d][0] = {0,0,0,0}; acc[d][1] = {0,0,0,0}; }

  // ---- prologue: stage chunk 0; hoist all F1 A-fragments (no LDS for F1)
  bf16x8 afrag[NCH];
  {
    float4 ld[NLD];
    stage_load(0, ld);
    const float* f1p = F1 + (((size_t)b * H + h0 + r) * W + wb0 + j) * C + kq * 8;
    float4 u[NCH][2];
#pragma unroll
    for (int ch = 0; ch < NCH; ++ch) {
      u[ch][0] = *reinterpret_cast<const float4*>(f1p + ch * CK);
      u[ch][1] = *reinterpret_cast<const float4*>(f1p + ch * CK + 4);
    }
    stage_store(0, ld);
#pragma unroll
    for (int ch = 0; ch < NCH; ++ch) {
      u32x4 q;
      q.x = bfpack2(u[ch][0].x, u[ch][0].y);
      q.y = bfpack2(u[ch][0].z, u[ch][0].w);
      q.z = bfpack2(u[ch][1].x, u[ch][1].y);
      q.w = bfpack2(u[ch][1].z, u[ch][1].w);
      afrag[ch] = __builtin_bit_cast(bf16x8, q);
    }
    __syncthreads();
  }

  // ---- pipelined K loop: issue loads early, compute, write LDS late, barrier
#pragma unroll
  for (int ch = 0; ch < NCH; ++ch) {
    float4 ld[NLD];
    if (ch + 1 < NCH) stage_load(ch + 1, ld);

    const short* base = &sF2[ch & 1][(r * F2S + j) * CK + kq * 8];
#pragma unroll
    for (int dy = 0; dy < 9; ++dy) {
      const bf16x8 b0 = *reinterpret_cast<const bf16x8*>(base + dy * RSTR);
      const bf16x8 b1 = *reinterpret_cast<const bf16x8*>(base + dy * RSTR + 16 * CK);
      acc[dy][0] = __builtin_amdgcn_mfma_f32_16x16x32_bf16(afrag[ch], b0, acc[dy][0], 0, 0, 0);
      acc[dy][1] = __builtin_amdgcn_mfma_f32_16x16x32_bf16(afrag[ch], b1, acc[dy][1], 0, 0, 0);
    }

    if (ch + 1 < NCH) {
      stage_store((ch + 1) & 1, ld);
      __syncthreads();
    }
  }

  // ---- epilogue: band extract, /128, leaky_relu(0.1), store
  // D layout: n = j (F2 col), m = kq*4 + reg (pixel i); dxi = j + 16t - i
  const int h = h0 + r;
  float* outb = out + (((size_t)b * H + h) * W + wb0) * NOFF;
#pragma unroll
  for (int dy = 0; dy < 9; ++dy) {
#pragma unroll
    for (int t = 0; t < 2; ++t) {
#pragma unroll
      for (int reg = 0; reg < 4; ++reg) {
        const int i   = kq * 4 + reg;
        const int dxi = j + t * 16 - i;
        if (dxi >= 0 && dxi <= 8) {
          float m = acc[dy][t][reg] * 0.0078125f;
          m = (m > 0.f) ? m : 0.1f * m;
          outb[(size_t)i * NOFF + dy * MO + dxi] = m;
        }
      }
    }
  }
}

extern "C" void kernel_launch(void* const* d_in, const int* in_sizes, int n_in,
                              void* d_out, int out_size, void* d_ws, size_t ws_size,
                              hipStream_t stream) {
  const float* F1 = (const float*)d_in[0];
  const float* F2 = (const float*)d_in[1];
  float* out = (float*)d_out;
  dim3 grid(B * (H / ROWS) * (W / WCOLS));  // 8 * 32 * 8 = 2048 blocks
  dim3 block(NT);                           // 256 threads = 4 waves
  hipLaunchKernelGGL(costvol_kernel, grid, block, 0, stream, F1, F2, out);
}

// Round 5
// 44.915 us; speedup vs baseline: 2.8090x; 1.1220x over previous
//
#include <hip/hip_runtime.h>
#include <hip/hip_bf16.h>
#include <string.h>

typedef __attribute__((ext_vector_type(8))) short bf16x8;
typedef __attribute__((ext_vector_type(4))) float f32x4;

namespace {
constexpr int B = 8, H = 128, W = 128, C = 128;
constexpr int MO = 9, NOFF = 81;
constexpr int ROWS = 4;          // output rows per block (1 per wave)
constexpr int WCOLS = 16;        // output cols per block
constexpr int F2R = 12;          // staged F2 rows (4 + 2*4 halo)
constexpr int F2S = 32;          // F2 col pitch: 24 real + 8 don't-care
constexpr int SREAL = 24;        // real staged cols (fx = wb0-4 .. wb0+19)
constexpr int CK = 32;           // channels per chunk (one MFMA K)
constexpr int NCH = C / CK;      // 4
constexpr int NT = 256;          // 4 waves
constexpr int NLD = 9;           // 12*24*8 / 256 staging float4 per thread
constexpr int RSTR = F2S * CK;   // shorts per staged F2 row (1024)
}

__device__ inline unsigned bf2pack(float a, float b) {
  // RTNE fp32->bf16 pair via v_cvt_pk_bf16_f32 (a = low half)
  __hip_bfloat162 h = __float22bfloat162_rn(float2{a, b});
  unsigned r;
  memcpy(&r, &h, sizeof(r));
  return r;
}

__global__ __launch_bounds__(NT, 3) void costvol_kernel(
    const float* __restrict__ F1, const float* __restrict__ F2,
    float* __restrict__ out)
{
  __shared__ __align__(16) short sF2[2][F2R * RSTR];  // 2 x 24 KB

  // b = lin&7: one batch per XCD; rt fastest: consecutive blocks share halo rows
  const int lin  = blockIdx.x;
  const int b    = lin & 7;
  const int tile = lin >> 3;      // 0..255
  const int rt   = tile & 31;
  const int wt   = tile >> 5;     // 0..7
  const int h0   = rt * ROWS;
  const int wb0  = wt * WCOLS;

  const int tid  = threadIdx.x;
  const int r    = tid >> 6;      // wave index = output row in tile
  const int lane = tid & 63;
  const int j    = lane & 15;     // MFMA m/n index
  const int kq   = lane >> 4;     // k-quarter

  // ---- loop-invariant staging decode: (ry, s, kg) per slot.
  // OOB slots get offset 0 (always-valid address); zeroing happens at pack.
  int gofs[NLD]; int lofs[NLD]; unsigned okmask = 0;
#pragma unroll
  for (int it = 0; it < NLD; ++it) {
    const int idx  = tid + it * NT;     // 0..2303
    const int kg   = idx & 7;
    const int slot = idx >> 3;          // 0..287
    const int ry   = slot / SREAL;
    const int s    = slot - ry * SREAL;
    const int fy   = h0 - 4 + ry;
    const int fx   = wb0 - 4 + s;
    const bool ok  = ((unsigned)fy < (unsigned)H) && ((unsigned)fx < (unsigned)W);
    okmask |= (unsigned)ok << it;
    gofs[it] = ok ? (((b * H + fy) * W + fx) * C + kg * 4) : 0;
    lofs[it] = (ry * F2S + s) * CK + kg * 4;
  }

  auto stage_load = [&](int ch, float4* ld) {
#pragma unroll
    for (int it = 0; it < NLD; ++it) {
      ld[it] = *reinterpret_cast<const float4*>(F2 + gofs[it] + ch * CK);
    }
    __builtin_amdgcn_sched_barrier(0);  // pin: loads must issue before compute
  };
  auto stage_store = [&](int buf, const float4* ld) {
#pragma unroll
    for (int it = 0; it < NLD; ++it) {
      uint2 p;
      p.x = bf2pack(ld[it].x, ld[it].y);
      p.y = bf2pack(ld[it].z, ld[it].w);
      if (!((okmask >> it) & 1u)) { p.x = 0u; p.y = 0u; }
      *reinterpret_cast<uint2*>(&sF2[buf][lofs[it]]) = p;
    }
  };

  f32x4 acc[9][2];
#pragma unroll
  for (int d = 0; d < 9; ++d) { acc[d][0] = {0,0,0,0}; acc[d][1] = {0,0,0,0}; }

  // ---- prologue: stage chunk 0; hoist all F1 A-fragments (no LDS for F1)
  bf16x8 afrag[NCH];
  {
    float4 ld[NLD];
    stage_load(0, ld);
    const float* f1p = F1 + (((size_t)b * H + h0 + r) * W + wb0 + j) * C + kq * 8;
    float4 u[NCH][2];
#pragma unroll
    for (int ch = 0; ch < NCH; ++ch) {
      u[ch][0] = *reinterpret_cast<const float4*>(f1p + ch * CK);
      u[ch][1] = *reinterpret_cast<const float4*>(f1p + ch * CK + 4);
    }
    stage_store(0, ld);
#pragma unroll
    for (int ch = 0; ch < NCH; ++ch) {
      uint4 q;
      q.x = bf2pack(u[ch][0].x, u[ch][0].y);
      q.y = bf2pack(u[ch][0].z, u[ch][0].w);
      q.z = bf2pack(u[ch][1].x, u[ch][1].y);
      q.w = bf2pack(u[ch][1].z, u[ch][1].w);
      afrag[ch] = __builtin_bit_cast(bf16x8, q);
    }
    __syncthreads();
  }

  // ---- pipelined K loop: [issue loads][fence][MFMA][fence][pack+store][bar]
#pragma unroll
  for (int ch = 0; ch < NCH; ++ch) {
    float4 ld[NLD];
    if (ch + 1 < NCH) stage_load(ch + 1, ld);

    const short* base = &sF2[ch & 1][(r * F2S + j) * CK + kq * 8];
#pragma unroll
    for (int dy = 0; dy < 9; ++dy) {
      const bf16x8 b0 = *reinterpret_cast<const bf16x8*>(base + dy * RSTR);
      const bf16x8 b1 = *reinterpret_cast<const bf16x8*>(base + dy * RSTR + 16 * CK);
      acc[dy][0] = __builtin_amdgcn_mfma_f32_16x16x32_bf16(afrag[ch], b0, acc[dy][0], 0, 0, 0);
      acc[dy][1] = __builtin_amdgcn_mfma_f32_16x16x32_bf16(afrag[ch], b1, acc[dy][1], 0, 0, 0);
    }

    if (ch + 1 < NCH) {
      __builtin_amdgcn_sched_barrier(0);  // pin: pack/store stays after MFMA
      stage_store((ch + 1) & 1, ld);
      __syncthreads();
    }
  }

  // ---- epilogue: band extract, /128, leaky_relu(0.1), store
  // D layout: n = j (F2 col), m = kq*4 + reg (pixel i); dxi = j + 16t - i
  const int h = h0 + r;
  float* outb = out + (((size_t)b * H + h) * W + wb0) * NOFF;
#pragma unroll
  for (int dy = 0; dy < 9; ++dy) {
#pragma unroll
    for (int t = 0; t < 2; ++t) {
#pragma unroll
      for (int reg = 0; reg < 4; ++reg) {
        const int i   = kq * 4 + reg;
        const int dxi = j + t * 16 - i;
        if (dxi >= 0 && dxi <= 8) {
          float m = acc[dy][t][reg] * 0.0078125f;
          m = (m > 0.f) ? m : 0.1f * m;
          outb[(size_t)i * NOFF + dy * MO + dxi] = m;
        }
      }
    }
  }
}

extern "C" void kernel_launch(void* const* d_in, const int* in_sizes, int n_in,
                              void* d_out, int out_size, void* d_ws, size_t ws_size,
                              hipStream_t stream) {
  const float* F1 = (const float*)d_in[0];
  const float* F2 = (const float*)d_in[1];
  float* out = (float*)d_out;
  dim3 grid(B * (H / ROWS) * (W / WCOLS));  // 8 * 32 * 8 = 2048 blocks
  dim3 block(NT);                           // 256 threads = 4 waves
  hipLaunchKernelGGL(costvol_kernel, grid, block, 0, stream, F1, F2, out);
}